// Round 1
// 154.462 us; speedup vs baseline: 1.0337x; 1.0337x over previous
//
#include <hip/hip_runtime.h>
#include <math.h>

#define B_  16
#define C_  512
#define A_  64
#define CV  448     // C - A (value / z_img dims)
#define G_  256
#define HW  256
#define SMX 256     // padded S (Smax)
#define BSP 8       // b-rows per block (2 blocks per group)

// ---------------- Kernel 1: spatial mean pool  z[b,c] = mean(Z_img[b,c,:,:]) ----
__global__ __launch_bounds__(256) void meanpool_kernel(const float* __restrict__ Zimg,
                                                       float* __restrict__ z) {
  int row  = (blockIdx.x << 2) + (threadIdx.x >> 6);   // b*C + c
  int lane = threadIdx.x & 63;
  const float4* p = (const float4*)(Zimg + (size_t)row * HW);
  float4 v = p[lane];
  float s = (v.x + v.y) + (v.z + v.w);
  #pragma unroll
  for (int off = 32; off > 0; off >>= 1)
    s += __shfl_down(s, off, 64);
  if (lane == 0) z[row] = s * (1.0f / HW);
}

// ---------------- Kernel 2: fused scores + softmax + PV + M_img ---------------
// grid = G_*2. g = bid&255, bh = bid>>8 selects 8 b-rows. Blocks bid and
// bid+256 share bid&7 => same XCD => key/value rows deduped in that L2.
// Phase A: thread (s = t>>1, kh = t&1) computes a 32-dim half-dot for 8 b,
//          combines via shfl_xor(1); block-wide softmax over s; attn -> LDS.
// Phase B: wave = (column-chunk ch, s-parity sh); lane = (col slot cl, s
//          sub-parity h). 8 gathered float4/thread in flight; attn reads are
//          wave-broadcast; cross-wave combine via LDS redS + shfl_xor(32).
__global__ __launch_bounds__(512, 4) void fused_kernel(
    const float* __restrict__ Zsnd,
    const int*   __restrict__ pad_idx,
    const float* __restrict__ z,
    float*       __restrict__ Mimg,
    float*       __restrict__ Msnd,
    int Smax, int N)
{
  const int bid  = blockIdx.x;
  const int g    = bid & 255;
  const int bh   = bid >> 8;
  const int b0   = bh * BSP;
  const int t    = threadIdx.x;
  const int lane = t & 63;
  const int wave = t >> 6;

  __shared__ float qs[BSP * A_];            // 2 KB
  __shared__ float attnT[SMX * BSP];        // 8 KB  [s][b-local]
  __shared__ int   idxs[SMX];               // 1 KB
  __shared__ float red[8 * BSP];
  __shared__ float red2[8 * BSP];
  __shared__ int   redi[8];
  __shared__ float redS[4 * BSP * 64 * 4];  // 32 KB [ch][b][lane] float4

  // ---- stage: validity/idx, queries, M_img broadcast ----
  int sgv = 0;
  if (t < SMX) {
    int v = pad_idx[(size_t)g * Smax + t];
    bool ok = ((t == 0) || (v != 0)) && (v >= 0) && (v < N);
    idxs[t] = ok ? v : 0;
    sgv = ok ? (t + 1) : 0;
  }
  #pragma unroll
  for (int off = 32; off > 0; off >>= 1)
    sgv = max(sgv, __shfl_xor(sgv, off, 64));
  if (lane == 0) redi[wave] = sgv;

  if (t < BSP * 16) {                       // 8 b x 16 a4 = 128 float4s
    int b = t >> 4, a4 = t & 15;
    *(float4*)(qs + b * A_ + a4 * 4) =
        *(const float4*)(z + (b0 + b) * C_ + CV + a4 * 4);
  }

  {                                         // Mimg[g, b0+b, :] = z[b0+b, :CV]
    int b = t >> 6, c = t & 63;
    float* mrow = Mimg + (size_t)g * (B_ * CV) + (b0 + b) * CV;
    const float* zrow = z + (b0 + b) * C_;
    *(float4*)(mrow + c * 4) = *(const float4*)(zrow + c * 4);
    int c2 = c + 64;
    if (c2 < 112)
      *(float4*)(mrow + c2 * 4) = *(const float4*)(zrow + c2 * 4);
  }

  __syncthreads();
  const int sg = max(max(max(redi[0], redi[1]), max(redi[2], redi[3])),
                     max(max(redi[4], redi[5]), max(redi[6], redi[7])));

  // ---- Phase A: scores (split-K over kh) ----
  const int s_ = t >> 1;
  const int kh = t & 1;
  const bool valid = (s_ < sg);             // prefix-contiguous validity
  const float* krow = Zsnd + (size_t)idxs[s_] * C_ + CV + kh * 32;

  float sc[BSP];
  #pragma unroll
  for (int b = 0; b < BSP; b++) sc[b] = 0.0f;

  #pragma unroll
  for (int c = 0; c < 2; c++) {
    float4 k0 = *(const float4*)(krow + c * 16 + 0);
    float4 k1 = *(const float4*)(krow + c * 16 + 4);
    float4 k2 = *(const float4*)(krow + c * 16 + 8);
    float4 k3 = *(const float4*)(krow + c * 16 + 12);
    #pragma unroll
    for (int b = 0; b < BSP; b++) {
      const float* qb = qs + b * A_ + kh * 32 + c * 16;
      float4 q0 = *(const float4*)(qb + 0);
      float4 q1 = *(const float4*)(qb + 4);
      float4 q2 = *(const float4*)(qb + 8);
      float4 q3 = *(const float4*)(qb + 12);
      sc[b] += q0.x * k0.x + q0.y * k0.y + q0.z * k0.z + q0.w * k0.w
             + q1.x * k1.x + q1.y * k1.y + q1.z * k1.z + q1.w * k1.w
             + q2.x * k2.x + q2.y * k2.y + q2.z * k2.z + q2.w * k2.w
             + q3.x * k3.x + q3.y * k3.y + q3.z * k3.z + q3.w * k3.w;
    }
    __builtin_amdgcn_sched_barrier(0);      // cap live values (anti-spill)
  }
  #pragma unroll
  for (int b = 0; b < BSP; b++)
    sc[b] += __shfl_xor(sc[b], 1, 64);      // combine kh halves: full dot

  // ---- softmax over s (butterfly within wave, LDS across 8 waves) ----
  #pragma unroll
  for (int b = 0; b < BSP; b++) {
    float v = valid ? sc[b] : -INFINITY;
    #pragma unroll
    for (int off = 32; off > 0; off >>= 1)
      v = fmaxf(v, __shfl_xor(v, off, 64));
    if (lane == 0) red[wave * BSP + b] = v;
  }
  __syncthreads();

  float ex[BSP];
  #pragma unroll
  for (int b = 0; b < BSP; b++) {
    float gm = red[0 * BSP + b];
    #pragma unroll
    for (int w2 = 1; w2 < 8; w2++) gm = fmaxf(gm, red[w2 * BSP + b]);
    float e = valid ? __expf(sc[b] - gm) : 0.0f;
    ex[b] = e;
    float es = (kh == 0) ? e : 0.0f;        // count each s once
    #pragma unroll
    for (int off = 32; off > 0; off >>= 1)
      es += __shfl_xor(es, off, 64);
    if (lane == 0) red2[wave * BSP + b] = es;
  }
  __syncthreads();

  if (kh == 0) {
    float iv[BSP];
    #pragma unroll
    for (int b = 0; b < BSP; b++) {
      float gs = red2[0 * BSP + b];
      #pragma unroll
      for (int w2 = 1; w2 < 8; w2++) gs += red2[w2 * BSP + b];
      iv[b] = ex[b] / gs;
    }
    *(float4*)(attnT + s_ * BSP + 0) = make_float4(iv[0], iv[1], iv[2], iv[3]);
    *(float4*)(attnT + s_ * BSP + 4) = make_float4(iv[4], iv[5], iv[6], iv[7]);
  }
  __syncthreads();

  // ---- Phase B: weighted value sum ----
  const int ch = wave >> 1;                 // column chunk (0..3)
  const int sh = wave & 1;                  // s parity
  const int cl = lane & 31;                 // float4 column slot
  const int h  = lane >> 5;                 // s sub-parity
  const int c0 = ch * 128;
  const int sg32 = (sg + 31) & ~31;

  const float* vbase = Zsnd + c0 + cl * 4;  // + idx*C_ ; col <= 508 in-row
  float4 acc[BSP];
  #pragma unroll
  for (int b = 0; b < BSP; b++) acc[b] = make_float4(0.f, 0.f, 0.f, 0.f);

  for (int s0 = 0; s0 < sg32; s0 += 32) {
    float4 v[8];
    #pragma unroll
    for (int j = 0; j < 8; j++) {
      int so = s0 + 4 * j + 2 * sh + h;
      v[j] = *(const float4*)(vbase + (size_t)idxs[so] * C_);
    }
    #pragma unroll
    for (int j = 0; j < 8; j++) {
      int so = s0 + 4 * j + 2 * sh + h;
      float4 w0 = *(const float4*)(attnT + so * BSP + 0);   // b 0..3 (broadcast)
      float4 w1 = *(const float4*)(attnT + so * BSP + 4);   // b 4..7
      float4 vv = v[j];
      acc[0].x += w0.x * vv.x; acc[0].y += w0.x * vv.y; acc[0].z += w0.x * vv.z; acc[0].w += w0.x * vv.w;
      acc[1].x += w0.y * vv.x; acc[1].y += w0.y * vv.y; acc[1].z += w0.y * vv.z; acc[1].w += w0.y * vv.w;
      acc[2].x += w0.z * vv.x; acc[2].y += w0.z * vv.y; acc[2].z += w0.z * vv.z; acc[2].w += w0.z * vv.w;
      acc[3].x += w0.w * vv.x; acc[3].y += w0.w * vv.y; acc[3].z += w0.w * vv.z; acc[3].w += w0.w * vv.w;
      acc[4].x += w1.x * vv.x; acc[4].y += w1.x * vv.y; acc[4].z += w1.x * vv.z; acc[4].w += w1.x * vv.w;
      acc[5].x += w1.y * vv.x; acc[5].y += w1.y * vv.y; acc[5].z += w1.y * vv.z; acc[5].w += w1.y * vv.w;
      acc[6].x += w1.z * vv.x; acc[6].y += w1.z * vv.y; acc[6].z += w1.z * vv.z; acc[6].w += w1.z * vv.w;
      acc[7].x += w1.w * vv.x; acc[7].y += w1.w * vv.y; acc[7].z += w1.w * vv.z; acc[7].w += w1.w * vv.w;
    }
  }

  // ---- cross-wave combine: sh==1 partials -> LDS, sh==0 adds + h-shfl ----
  if (sh == 1) {
    #pragma unroll
    for (int b = 0; b < BSP; b++)
      *(float4*)(redS + (((size_t)ch * BSP + b) * 64 + lane) * 4) = acc[b];
  }
  __syncthreads();
  if (sh == 0) {
    #pragma unroll
    for (int b = 0; b < BSP; b++) {
      float4 o = *(const float4*)(redS + (((size_t)ch * BSP + b) * 64 + lane) * 4);
      acc[b].x += o.x; acc[b].y += o.y; acc[b].z += o.z; acc[b].w += o.w;
      acc[b].x += __shfl_xor(acc[b].x, 32, 64);
      acc[b].y += __shfl_xor(acc[b].y, 32, 64);
      acc[b].z += __shfl_xor(acc[b].z, 32, 64);
      acc[b].w += __shfl_xor(acc[b].w, 32, 64);
    }
    if (h == 0 && c0 + cl * 4 < CV) {
      float* obase = Msnd + (size_t)g * (B_ * CV) + (size_t)b0 * CV + c0 + cl * 4;
      #pragma unroll
      for (int b = 0; b < BSP; b++)
        *(float4*)(obase + b * CV) = acc[b];
    }
  }
}

extern "C" void kernel_launch(void* const* d_in, const int* in_sizes, int n_in,
                              void* d_out, int out_size, void* d_ws, size_t ws_size,
                              hipStream_t stream) {
  const float* Zimg   = (const float*)d_in[0];
  const float* Zsnd   = (const float*)d_in[1];
  const int*   padidx = (const int*)d_in[2];
  // d_in[3] = pad_mask (unused; validity derived from pad_idx)
  // d_in[4] = attn_dims (constant 64)

  const int N    = in_sizes[1] / C_;     // rows in Z_snd
  const int Smax = in_sizes[2] / G_;     // padded sequence length (== 256)

  float* z    = (float*)d_ws;            // B*C fp32 (only ws use now)
  float* Mimg = (float*)d_out;
  float* Msnd = Mimg + (size_t)G_ * B_ * CV;

  meanpool_kernel<<<(B_ * C_) / 4, 256, 0, stream>>>(Zimg, z);
  fused_kernel<<<G_ * 2, 512, 0, stream>>>(Zsnd, padidx, z, Mimg, Msnd, Smax, N);
}